// Round 9
// baseline (15062.358 us; speedup 1.0000x reference)
//
#include <hip/hip_runtime.h>
#include <hip/hip_cooperative_groups.h>
#include <cstddef>

namespace cg = cooperative_groups;

#define NROW 4096
#define DIM  512
static const size_t NP = (size_t)NROW * NROW;   // 16777216
#define L2E    1.4426950408889634f
#define ALPHA2 (-12.0f)          // -log2(4096), exact
#define QSCALE 64.0f             // S fp32 -> int16: q = rn(S*64), |S| << 512
#define QD     (1.4426950408889634f / 64.0f)   // dequant * log2e in one fma
#define NBLK   256               // 1 block/CU -- most conservative cooperative grid
#define RPB    16                // rows per block per phase (256*16 = 4096)

typedef unsigned int uint32;

// ---------------------------------------------------------------- sq norms
__global__ __launch_bounds__(256) void sqnorm_kernel(const float* __restrict__ x,
                                                     const float* __restrict__ y,
                                                     float* __restrict__ x2,
                                                     float* __restrict__ y2) {
    int gtid = blockIdx.x * 256 + threadIdx.x;
    int wid  = gtid >> 6;          // 8192 waves: 0..4095 -> x, 4096..8191 -> y
    int lane = gtid & 63;
    const float* src = (wid < NROW) ? x : y;
    float*       dst = (wid < NROW) ? x2 : y2;
    int row = (wid < NROW) ? wid : (wid - NROW);
    const float4* r4 = (const float4*)(src + (size_t)row * DIM);
    float4 a = r4[lane];
    float4 b = r4[lane + 64];
    float s = a.x*a.x + a.y*a.y + a.z*a.z + a.w*a.w
            + b.x*b.x + b.y*b.y + b.z*b.z + b.w*b.w;
    #pragma unroll
    for (int off = 32; off > 0; off >>= 1) s += __shfl_down(s, off);
    if (lane == 0) dst[row] = s;
}

// ---------------------------------------------------------------- S = 2 x y^T  (fp32)
__global__ __launch_bounds__(256) void gemm_kernel(const float* __restrict__ A,
                                                   const float* __restrict__ B,
                                                   float* __restrict__ S) {
    __shared__ float As[16][132];
    __shared__ float Bs[16][132];
    const int bm = blockIdx.y * 128, bn = blockIdx.x * 128;
    const int tid = threadIdx.x;
    const int tx = tid & 15, ty = tid >> 4;
    float acc[8][8];
    #pragma unroll
    for (int i = 0; i < 8; ++i)
        #pragma unroll
        for (int j = 0; j < 8; ++j) acc[i][j] = 0.f;

    for (int kt = 0; kt < DIM; kt += 16) {
        #pragma unroll
        for (int h = 0; h < 2; ++h) {
            int f = tid + h * 256;
            int row = f >> 2, kk = (f & 3) << 2;
            float4 a4 = *(const float4*)(A + (size_t)(bm + row) * DIM + kt + kk);
            As[kk+0][row] = a4.x; As[kk+1][row] = a4.y;
            As[kk+2][row] = a4.z; As[kk+3][row] = a4.w;
            float4 b4 = *(const float4*)(B + (size_t)(bn + row) * DIM + kt + kk);
            Bs[kk+0][row] = b4.x; Bs[kk+1][row] = b4.y;
            Bs[kk+2][row] = b4.z; Bs[kk+3][row] = b4.w;
        }
        __syncthreads();
        #pragma unroll
        for (int k = 0; k < 16; ++k) {
            float ar[8], br[8];
            #pragma unroll
            for (int i = 0; i < 8; ++i) ar[i] = As[k][ty*8 + i];
            #pragma unroll
            for (int j = 0; j < 8; ++j) br[j] = Bs[k][tx*8 + j];
            #pragma unroll
            for (int i = 0; i < 8; ++i)
                #pragma unroll
                for (int j = 0; j < 8; ++j)
                    acc[i][j] = __fmaf_rn(ar[i], br[j], acc[i][j]);
        }
        __syncthreads();
    }
    #pragma unroll
    for (int i = 0; i < 8; ++i) {
        size_t off = (size_t)(bm + ty*8 + i) * NROW + bn + tx*8;
        #pragma unroll
        for (int j = 0; j < 8; ++j) S[off + j] = 2.0f * acc[i][j];
    }
}

// ---------------------------------------------------------------- quantize S -> Sq (+ zero cost)
__global__ __launch_bounds__(256) void quantA_kernel(const float* __restrict__ S,
                                                     uint32* __restrict__ Sq,
                                                     float* __restrict__ cost) {
    if (blockIdx.x == 0 && threadIdx.x == 0) cost[0] = 0.f;
    size_t i = (size_t)blockIdx.x * 256 + threadIdx.x;     // uint index
    const size_t nu = NP / 2, stride = (size_t)2048 * 256;
    for (; i < nu; i += stride) {
        float a = S[2*i], b = S[2*i + 1];
        float qa = fmaxf(fminf(a * QSCALE,  32767.f), -32767.f);
        float qb = fmaxf(fminf(b * QSCALE,  32767.f), -32767.f);
        int ia = __float2int_rn(qa), ib = __float2int_rn(qb);
        Sq[i] = (uint32)(ia & 0xffff) | ((uint32)ib << 16);
    }
}

// ---------------------------------------------------------------- quantize+transpose S -> SqT
__global__ __launch_bounds__(256) void quantT_kernel(const float* __restrict__ S,
                                                     uint32* __restrict__ SqT) {
    __shared__ short tile[64][66];
    const int bx = blockIdx.x * 64, by = blockIdx.y * 64;
    const int t = threadIdx.x;
    const int c = t & 63, r0 = t >> 6;
    #pragma unroll
    for (int rr = 0; rr < 16; ++rr) {
        int r = r0 + rr * 4;
        float v = S[(size_t)(by + r) * NROW + bx + c];
        float q = fmaxf(fminf(v * QSCALE, 32767.f), -32767.f);
        tile[r][c] = (short)__float2int_rn(q);
    }
    __syncthreads();
    const int p = t & 31, jl = t >> 5;
    #pragma unroll
    for (int jj = 0; jj < 8; ++jj) {
        int j = jj * 8 + jl;
        uint32 lo = (unsigned short)tile[2*p    ][j];
        uint32 hi = (unsigned short)tile[2*p + 1][j];
        SqT[(size_t)(bx + j) * (NROW/2) + (by >> 1) + p] = lo | (hi << 16);
    }
}

// ---------------------------------------------------------------- init (gt2 only)
__global__ void init_kernel(const float* __restrict__ y2,
                            float* __restrict__ gt2) {
    int i = blockIdx.x * 256 + threadIdx.x;
    if (i < NROW) gt2[i] = -y2[i] * L2E;       // g~0 = -y2, in base-2 units
}

// ---------------------------------------------------------------- fused-iteration lse phase
__device__ __forceinline__ void lse_rows(const uint32* __restrict__ Q,
                                         const float* __restrict__ u2,
                                         float* __restrict__ o2,
                                         int r0, int t) {
    float m[RPB], s[RPB];
    #pragma unroll
    for (int r = 0; r < RPB; ++r) { m[r] = -1e30f; s[r] = 0.f; }
    const uint32* q = Q + (size_t)r0 * (NROW/2);
    for (int h = 0; h < 8; ++h) {
        int k = t + h * 256;                          // int16-pair index
        float2 uu = *(const float2*)(u2 + 2*k);
        #pragma unroll
        for (int r = 0; r < RPB; ++r) {
            uint32 w = q[(size_t)r * (NROW/2) + k];
            float a = (float)(int)(short)(w & 0xffffu);
            float b = (float)((int)w >> 16);
            float va = fmaf(a, QD, uu.x);
            float vb = fmaf(b, QD, uu.y);
            float vm = fmaxf(va, vb);
            if (__any(vm > m[r] + 60.f)) {            // rare wave-uniform rescale
                float mn = fmaxf(m[r], vm);
                s[r] *= exp2f(m[r] - mn);
                m[r] = mn;
            }
            s[r] += exp2f(va - m[r]) + exp2f(vb - m[r]);
        }
    }
    // 64-lane butterfly merge per row
    #pragma unroll
    for (int off = 1; off < 64; off <<= 1) {
        #pragma unroll
        for (int r = 0; r < RPB; ++r) {
            float mo = __shfl_xor(m[r], off), so = __shfl_xor(s[r], off);
            float d = m[r] - mo;
            float e = exp2f(-fabsf(d));
            s[r] = (d > 0.f) ? fmaf(so, e, s[r]) : fmaf(s[r], e, so);
            m[r] = fmaxf(m[r], mo);
        }
    }
    __shared__ float sm[4][RPB], ss[4][RPB];
    int lane = t & 63, w = t >> 6;
    if (lane == 0) {
        #pragma unroll
        for (int r = 0; r < RPB; ++r) { sm[w][r] = m[r]; ss[w][r] = s[r]; }
    }
    __syncthreads();
    if (t < RPB) {
        float M = sm[0][t], S = ss[0][t];
        #pragma unroll
        for (int w2 = 1; w2 < 4; ++w2) {
            float d = M - sm[w2][t];
            float e = exp2f(-fabsf(d));
            S = (d > 0.f) ? fmaf(ss[w2][t], e, S) : fmaf(S, e, ss[w2][t]);
            M = fmaxf(M, sm[w2][t]);
        }
        o2[r0 + t] = ALPHA2 - (M + __log2f(S));
    }
    // caller's grid.sync() also block-syncs, protecting sm/ss reuse
}

__global__ __launch_bounds__(256) void sink_iter_kernel(
        const uint32* __restrict__ Sq, const uint32* __restrict__ SqT,
        float* __restrict__ ft2, float* __restrict__ gt2) {
    cg::grid_group grid = cg::this_grid();
    const int t = threadIdx.x;
    const int r0 = blockIdx.x * RPB;
    for (int it = 0; it < 100; ++it) {
        lse_rows(Sq,  gt2, ft2, r0, t);               // f update
        grid.sync();
        lse_rows(SqT, ft2, gt2, r0, t);               // g update
        grid.sync();
    }
}

// ---------------------------------------------------------------- fallback lse pass (round-6, proven)
__global__ __launch_bounds__(256) void lseq_kernel(const uint32* __restrict__ Q,
                                                   const float* __restrict__ u2,
                                                   float* __restrict__ o2) {
    const int r0 = blockIdx.x * 2;
    const uint32* q0 = Q + (size_t)r0 * (NROW/2);
    const uint32* q1 = q0 + (NROW/2);
    const int t = threadIdx.x;
    float m0 = -1e30f, s0 = 0.f, m1 = -1e30f, s1 = 0.f;
    #pragma unroll 2
    for (int h = 0; h < 8; ++h) {
        int k = t + h * 256;
        float2 uu = *(const float2*)(u2 + 2*k);
        uint32 w0 = q0[k], w1 = q1[k];
        float a0 = (float)(int)(short)(w0 & 0xffffu);
        float b0 = (float)((int)w0 >> 16);
        float a1 = (float)(int)(short)(w1 & 0xffffu);
        float b1 = (float)((int)w1 >> 16);
        float v00 = fmaf(a0, QD, uu.x), v01 = fmaf(b0, QD, uu.y);
        float v10 = fmaf(a1, QD, uu.x), v11 = fmaf(b1, QD, uu.y);
        float vm0 = fmaxf(v00, v01), vm1 = fmaxf(v10, v11);
        if (__any(vm0 > m0 + 60.f)) {
            float mn = fmaxf(m0, vm0);
            s0 *= exp2f(m0 - mn); m0 = mn;
        }
        if (__any(vm1 > m1 + 60.f)) {
            float mn = fmaxf(m1, vm1);
            s1 *= exp2f(m1 - mn); m1 = mn;
        }
        s0 += exp2f(v00 - m0) + exp2f(v01 - m0);
        s1 += exp2f(v10 - m1) + exp2f(v11 - m1);
    }
    #pragma unroll
    for (int off = 1; off < 64; off <<= 1) {
        float mo = __shfl_xor(m0, off), so = __shfl_xor(s0, off);
        float d = m0 - mo;
        float e = exp2f(-fabsf(d));
        s0 = (d > 0.f) ? fmaf(so, e, s0) : fmaf(s0, e, so);
        m0 = fmaxf(m0, mo);
        float mo1 = __shfl_xor(m1, off), so1 = __shfl_xor(s1, off);
        float d1 = m1 - mo1;
        float e1 = exp2f(-fabsf(d1));
        s1 = (d1 > 0.f) ? fmaf(so1, e1, s1) : fmaf(s1, e1, so1);
        m1 = fmaxf(m1, mo1);
    }
    __shared__ float sm0[4], ss0[4], sm1[4], ss1[4];
    int lane = t & 63, w = t >> 6;
    if (lane == 0) { sm0[w] = m0; ss0[w] = s0; sm1[w] = m1; ss1[w] = s1; }
    __syncthreads();
    if (t == 0) {
        float M0 = sm0[0], S0 = ss0[0], M1 = sm1[0], S1 = ss1[0];
        #pragma unroll
        for (int ww = 1; ww < 4; ++ww) {
            float d = M0 - sm0[ww];
            float e = exp2f(-fabsf(d));
            S0 = (d > 0.f) ? fmaf(ss0[ww], e, S0) : fmaf(S0, e, ss0[ww]);
            M0 = fmaxf(M0, sm0[ww]);
            float d1 = M1 - sm1[ww];
            float e1 = exp2f(-fabsf(d1));
            S1 = (d1 > 0.f) ? fmaf(ss1[ww], e1, S1) : fmaf(S1, e1, ss1[ww]);
            M1 = fmaxf(M1, sm1[ww]);
        }
        o2[r0]     = ALPHA2 - (M0 + __log2f(S0));
        o2[r0 + 1] = ALPHA2 - (M1 + __log2f(S1));
    }
}

// ---------------------------------------------------------------- finalize
__global__ __launch_bounds__(256) void finalize_kernel(const float* __restrict__ S,
                                                       const float* __restrict__ ft2,
                                                       const float* __restrict__ gt2,
                                                       const float* __restrict__ x2,
                                                       const float* __restrict__ y2,
                                                       float* __restrict__ pi,
                                                       float* __restrict__ C,
                                                       float* __restrict__ cost) {
    const int row = blockIdx.x;
    const size_t base = (size_t)row * NROW;
    const float fi2 = ft2[row];
    const float x2i = x2[row];
    float acc = 0.f;
    #pragma unroll
    for (int h = 0; h < 16; ++h) {
        int j = threadIdx.x + h * 256;
        float sv = S[base + j];                    // read BEFORE in-place C write
        float p  = exp2f(fmaf(sv, L2E, fi2 + gt2[j]));
        float c  = fmaxf(x2i + y2[j] - sv, 0.f);
        pi[base + j] = p;                          // clobbers Sq region (done with it)
        C[base + j]  = c;
        acc = __fmaf_rn(p, c, acc);
    }
    #pragma unroll
    for (int off = 32; off > 0; off >>= 1) acc += __shfl_down(acc, off);
    __shared__ float sa[4];
    int lane = threadIdx.x & 63, w = threadIdx.x >> 6;
    if (lane == 0) sa[w] = acc;
    __syncthreads();
    if (threadIdx.x == 0)
        atomicAdd(cost, sa[0] + sa[1] + sa[2] + sa[3]);
}

// ---------------------------------------------------------------- launch
extern "C" void kernel_launch(void* const* d_in, const int* in_sizes, int n_in,
                              void* d_out, int out_size, void* d_ws, size_t ws_size,
                              hipStream_t stream) {
    const float* x = (const float*)d_in[0];
    const float* y = (const float*)d_in[1];
    float* out  = (float*)d_out;
    float* cost = out;                 // [1]
    float* pi   = out + 1;             // [NP] floats; holds Sq|SqT (int16) during iters
    float* Cpt  = out + 1 + NP;        // [NP] floats; holds fp32 S during iters
    float* S    = Cpt;
    uint32* Sq  = (uint32*)pi;         // NP/2 uints = 32 MB
    uint32* SqT = Sq + NP/2;           // NP/2 uints = 32 MB (fills pi slot exactly)

    float* ws  = (float*)d_ws;         // small vectors only
    float* x2  = ws;
    float* y2  = ws + NROW;
    float* ft2 = ws + 2 * NROW;        // f~ in base-2 units
    float* gt2 = ws + 3 * NROW;        // g~ in base-2 units

    sqnorm_kernel<<<2048, 256, 0, stream>>>(x, y, x2, y2);
    gemm_kernel<<<dim3(32, 32), 256, 0, stream>>>(x, y, S);
    quantA_kernel<<<2048, 256, 0, stream>>>(S, Sq, cost);
    quantT_kernel<<<dim3(64, 64), 256, 0, stream>>>(S, SqT);
    init_kernel<<<16, 256, 0, stream>>>(y2, gt2);

    void* kargs[] = { (void*)&Sq, (void*)&SqT, (void*)&ft2, (void*)&gt2 };
    hipError_t cerr = hipLaunchCooperativeKernel((void*)sink_iter_kernel,
                                                 dim3(NBLK), dim3(256),
                                                 kargs, 0, stream);
    if (cerr != hipSuccess) {
        // fallback: proven 200-dispatch loop (round-6 path)
        for (int it = 0; it < 100; ++it) {
            lseq_kernel<<<2048, 256, 0, stream>>>(Sq,  gt2, ft2);
            lseq_kernel<<<2048, 256, 0, stream>>>(SqT, ft2, gt2);
        }
    }

    finalize_kernel<<<NROW, 256, 0, stream>>>(S, ft2, gt2, x2, y2, pi, Cpt, cost);
}

// Round 11
// 7297.339 us; speedup vs baseline: 2.0641x; 2.0641x over previous
//
#include <hip/hip_runtime.h>
#include <hip/hip_cooperative_groups.h>
#include <cstddef>

namespace cg = cooperative_groups;

#define NROW 4096
#define DIM  512
static const size_t NP = (size_t)NROW * NROW;   // 16777216
#define L2E    1.4426950408889634f
#define ALPHA2 (-12.0f)          // -log2(4096), exact
#define QSCALE 64.0f             // S fp32 -> int16: q = rn(S*64), |S| << 512
#define QD     (1.4426950408889634f / 64.0f)   // dequant * log2e in one fma
#define NBLK   256               // 1 block/CU -- cooperative validator accepts this
#define TPB    1024              // 16 waves/block -> 4 waves/SIMD (round-9 fix)
#define RPB    16                // rows per block per phase; wave w owns row r0+w

typedef unsigned int uint32;

// ---------------------------------------------------------------- sq norms
__global__ __launch_bounds__(256) void sqnorm_kernel(const float* __restrict__ x,
                                                     const float* __restrict__ y,
                                                     float* __restrict__ x2,
                                                     float* __restrict__ y2) {
    int gtid = blockIdx.x * 256 + threadIdx.x;
    int wid  = gtid >> 6;
    int lane = gtid & 63;
    const float* src = (wid < NROW) ? x : y;
    float*       dst = (wid < NROW) ? x2 : y2;
    int row = (wid < NROW) ? wid : (wid - NROW);
    const float4* r4 = (const float4*)(src + (size_t)row * DIM);
    float4 a = r4[lane];
    float4 b = r4[lane + 64];
    float s = a.x*a.x + a.y*a.y + a.z*a.z + a.w*a.w
            + b.x*b.x + b.y*b.y + b.z*b.z + b.w*b.w;
    #pragma unroll
    for (int off = 32; off > 0; off >>= 1) s += __shfl_down(s, off);
    if (lane == 0) dst[row] = s;
}

// ---------------------------------------------------------------- S = 2 x y^T  (fp32)
__global__ __launch_bounds__(256) void gemm_kernel(const float* __restrict__ A,
                                                   const float* __restrict__ B,
                                                   float* __restrict__ S) {
    __shared__ float As[16][132];
    __shared__ float Bs[16][132];
    const int bm = blockIdx.y * 128, bn = blockIdx.x * 128;
    const int tid = threadIdx.x;
    const int tx = tid & 15, ty = tid >> 4;
    float acc[8][8];
    #pragma unroll
    for (int i = 0; i < 8; ++i)
        #pragma unroll
        for (int j = 0; j < 8; ++j) acc[i][j] = 0.f;

    for (int kt = 0; kt < DIM; kt += 16) {
        #pragma unroll
        for (int h = 0; h < 2; ++h) {
            int f = tid + h * 256;
            int row = f >> 2, kk = (f & 3) << 2;
            float4 a4 = *(const float4*)(A + (size_t)(bm + row) * DIM + kt + kk);
            As[kk+0][row] = a4.x; As[kk+1][row] = a4.y;
            As[kk+2][row] = a4.z; As[kk+3][row] = a4.w;
            float4 b4 = *(const float4*)(B + (size_t)(bn + row) * DIM + kt + kk);
            Bs[kk+0][row] = b4.x; Bs[kk+1][row] = b4.y;
            Bs[kk+2][row] = b4.z; Bs[kk+3][row] = b4.w;
        }
        __syncthreads();
        #pragma unroll
        for (int k = 0; k < 16; ++k) {
            float ar[8], br[8];
            #pragma unroll
            for (int i = 0; i < 8; ++i) ar[i] = As[k][ty*8 + i];
            #pragma unroll
            for (int j = 0; j < 8; ++j) br[j] = Bs[k][tx*8 + j];
            #pragma unroll
            for (int i = 0; i < 8; ++i)
                #pragma unroll
                for (int j = 0; j < 8; ++j)
                    acc[i][j] = __fmaf_rn(ar[i], br[j], acc[i][j]);
        }
        __syncthreads();
    }
    #pragma unroll
    for (int i = 0; i < 8; ++i) {
        size_t off = (size_t)(bm + ty*8 + i) * NROW + bn + tx*8;
        #pragma unroll
        for (int j = 0; j < 8; ++j) S[off + j] = 2.0f * acc[i][j];
    }
}

// ---------------------------------------------------------------- quantize S -> Sq (+ zero cost)
__global__ __launch_bounds__(256) void quantA_kernel(const float* __restrict__ S,
                                                     uint32* __restrict__ Sq,
                                                     float* __restrict__ cost) {
    if (blockIdx.x == 0 && threadIdx.x == 0) cost[0] = 0.f;
    size_t i = (size_t)blockIdx.x * 256 + threadIdx.x;
    const size_t nu = NP / 2, stride = (size_t)2048 * 256;
    for (; i < nu; i += stride) {
        float a = S[2*i], b = S[2*i + 1];
        float qa = fmaxf(fminf(a * QSCALE,  32767.f), -32767.f);
        float qb = fmaxf(fminf(b * QSCALE,  32767.f), -32767.f);
        int ia = __float2int_rn(qa), ib = __float2int_rn(qb);
        Sq[i] = (uint32)(ia & 0xffff) | ((uint32)ib << 16);
    }
}

// ---------------------------------------------------------------- quantize+transpose S -> SqT
__global__ __launch_bounds__(256) void quantT_kernel(const float* __restrict__ S,
                                                     uint32* __restrict__ SqT) {
    __shared__ short tile[64][66];
    const int bx = blockIdx.x * 64, by = blockIdx.y * 64;
    const int t = threadIdx.x;
    const int c = t & 63, r0 = t >> 6;
    #pragma unroll
    for (int rr = 0; rr < 16; ++rr) {
        int r = r0 + rr * 4;
        float v = S[(size_t)(by + r) * NROW + bx + c];
        float q = fmaxf(fminf(v * QSCALE, 32767.f), -32767.f);
        tile[r][c] = (short)__float2int_rn(q);
    }
    __syncthreads();
    const int p = t & 31, jl = t >> 5;
    #pragma unroll
    for (int jj = 0; jj < 8; ++jj) {
        int j = jj * 8 + jl;
        uint32 lo = (unsigned short)tile[2*p    ][j];
        uint32 hi = (unsigned short)tile[2*p + 1][j];
        SqT[(size_t)(bx + j) * (NROW/2) + (by >> 1) + p] = lo | (hi << 16);
    }
}

// ---------------------------------------------------------------- init (gt2 only)
__global__ void init_kernel(const float* __restrict__ y2,
                            float* __restrict__ gt2) {
    int i = blockIdx.x * 256 + threadIdx.x;
    if (i < NROW) gt2[i] = -y2[i] * L2E;       // g~0 = -y2, in base-2 units
}

// ---------------------------------------------------------------- fused-iteration lse phase
// 16 waves/block, wave w reduces row r0+w fully in-wave. u staged in LDS as
// 4 stride-1 arrays (conflict-free ds_read_b32).
__device__ __forceinline__ void lse_phase(const uint32* __restrict__ Q,
                                          const float* __restrict__ u2,
                                          float* __restrict__ o2,
                                          float* __restrict__ u0, float* __restrict__ u1,
                                          float* __restrict__ us2, float* __restrict__ u3,
                                          int r0, int t, int w, int lane) {
    // stage u (16 KB) deinterleaved: u[4k..4k+3] -> u0[k],u1[k],us2[k],u3[k]
    {
        float4 v = ((const float4*)u2)[t];     // t in [0,1024), coalesced 16 KB
        u0[t] = v.x; u1[t] = v.y; us2[t] = v.z; u3[t] = v.w;
    }
    __syncthreads();
    const uint2* q2 = (const uint2*)(Q + (size_t)(r0 + w) * (NROW/2));
    float m = -1e30f, s = 0.f;
    #pragma unroll 4
    for (int h = 0; h < 16; ++h) {
        int k2 = lane + h * 64;                 // uint2 index: elements 4k2..4k2+3
        uint2 wv = q2[k2];
        float a0 = (float)(int)(short)(wv.x & 0xffffu);
        float b0 = (float)((int)wv.x >> 16);
        float a1 = (float)(int)(short)(wv.y & 0xffffu);
        float b1 = (float)((int)wv.y >> 16);
        float v0 = fmaf(a0, QD, u0[k2]);
        float v1 = fmaf(b0, QD, u1[k2]);
        float v2 = fmaf(a1, QD, us2[k2]);
        float v3 = fmaf(b1, QD, u3[k2]);
        float vm = fmaxf(fmaxf(v0, v1), fmaxf(v2, v3));
        if (__any(vm > m + 60.f)) {             // rare wave-uniform rescale
            float mn = fmaxf(m, vm);
            s *= exp2f(m - mn); m = mn;
        }
        s += (exp2f(v0 - m) + exp2f(v1 - m)) + (exp2f(v2 - m) + exp2f(v3 - m));
    }
    // 64-lane butterfly merge
    #pragma unroll
    for (int off = 1; off < 64; off <<= 1) {
        float mo = __shfl_xor(m, off), so = __shfl_xor(s, off);
        float d = m - mo;
        float e = exp2f(-fabsf(d));
        s = (d > 0.f) ? fmaf(so, e, s) : fmaf(s, e, so);
        m = fmaxf(m, mo);
    }
    if (lane == 0) o2[r0 + w] = ALPHA2 - (m + __log2f(s));
    // caller's grid.sync() separates this phase's LDS reads from next staging
}

__global__ __launch_bounds__(1024) void sink_iter_kernel(
        const uint32* __restrict__ Sq, const uint32* __restrict__ SqT,
        float* __restrict__ ft2, float* __restrict__ gt2) {
    cg::grid_group grid = cg::this_grid();
    __shared__ float u0[1024], u1[1024], us2[1024], u3[1024];   // 16 KB
    const int t = threadIdx.x;
    const int w = t >> 6, lane = t & 63;
    const int r0 = blockIdx.x * RPB;
    for (int it = 0; it < 100; ++it) {
        lse_phase(Sq,  gt2, ft2, u0, u1, us2, u3, r0, t, w, lane);  // f update
        grid.sync();
        lse_phase(SqT, ft2, gt2, u0, u1, us2, u3, r0, t, w, lane);  // g update
        grid.sync();
    }
}

// ---------------------------------------------------------------- fallback lse pass (proven)
__global__ __launch_bounds__(256) void lseq_kernel(const uint32* __restrict__ Q,
                                                   const float* __restrict__ u2,
                                                   float* __restrict__ o2) {
    const int r0 = blockIdx.x * 2;
    const uint32* q0 = Q + (size_t)r0 * (NROW/2);
    const uint32* q1 = q0 + (NROW/2);
    const int t = threadIdx.x;
    float m0 = -1e30f, s0 = 0.f, m1 = -1e30f, s1 = 0.f;
    #pragma unroll 2
    for (int h = 0; h < 8; ++h) {
        int k = t + h * 256;
        float2 uu = *(const float2*)(u2 + 2*k);
        uint32 w0 = q0[k], w1 = q1[k];
        float a0 = (float)(int)(short)(w0 & 0xffffu);
        float b0 = (float)((int)w0 >> 16);
        float a1 = (float)(int)(short)(w1 & 0xffffu);
        float b1 = (float)((int)w1 >> 16);
        float v00 = fmaf(a0, QD, uu.x), v01 = fmaf(b0, QD, uu.y);
        float v10 = fmaf(a1, QD, uu.x), v11 = fmaf(b1, QD, uu.y);
        float vm0 = fmaxf(v00, v01), vm1 = fmaxf(v10, v11);
        if (__any(vm0 > m0 + 60.f)) {
            float mn = fmaxf(m0, vm0);
            s0 *= exp2f(m0 - mn); m0 = mn;
        }
        if (__any(vm1 > m1 + 60.f)) {
            float mn = fmaxf(m1, vm1);
            s1 *= exp2f(m1 - mn); m1 = mn;
        }
        s0 += exp2f(v00 - m0) + exp2f(v01 - m0);
        s1 += exp2f(v10 - m1) + exp2f(v11 - m1);
    }
    #pragma unroll
    for (int off = 1; off < 64; off <<= 1) {
        float mo = __shfl_xor(m0, off), so = __shfl_xor(s0, off);
        float d = m0 - mo;
        float e = exp2f(-fabsf(d));
        s0 = (d > 0.f) ? fmaf(so, e, s0) : fmaf(s0, e, so);
        m0 = fmaxf(m0, mo);
        float mo1 = __shfl_xor(m1, off), so1 = __shfl_xor(s1, off);
        float d1 = m1 - mo1;
        float e1 = exp2f(-fabsf(d1));
        s1 = (d1 > 0.f) ? fmaf(so1, e1, s1) : fmaf(s1, e1, so1);
        m1 = fmaxf(m1, mo1);
    }
    __shared__ float sm0[4], ss0[4], sm1[4], ss1[4];
    int lane = t & 63, w = t >> 6;
    if (lane == 0) { sm0[w] = m0; ss0[w] = s0; sm1[w] = m1; ss1[w] = s1; }
    __syncthreads();
    if (t == 0) {
        float M0 = sm0[0], S0 = ss0[0], M1 = sm1[0], S1 = ss1[0];
        #pragma unroll
        for (int ww = 1; ww < 4; ++ww) {
            float d = M0 - sm0[ww];
            float e = exp2f(-fabsf(d));
            S0 = (d > 0.f) ? fmaf(ss0[ww], e, S0) : fmaf(S0, e, ss0[ww]);
            M0 = fmaxf(M0, sm0[ww]);
            float d1 = M1 - sm1[ww];
            float e1 = exp2f(-fabsf(d1));
            S1 = (d1 > 0.f) ? fmaf(ss1[ww], e1, S1) : fmaf(S1, e1, ss1[ww]);
            M1 = fmaxf(M1, sm1[ww]);
        }
        o2[r0]     = ALPHA2 - (M0 + __log2f(S0));
        o2[r0 + 1] = ALPHA2 - (M1 + __log2f(S1));
    }
}

// ---------------------------------------------------------------- finalize
__global__ __launch_bounds__(256) void finalize_kernel(const float* __restrict__ S,
                                                       const float* __restrict__ ft2,
                                                       const float* __restrict__ gt2,
                                                       const float* __restrict__ x2,
                                                       const float* __restrict__ y2,
                                                       float* __restrict__ pi,
                                                       float* __restrict__ C,
                                                       float* __restrict__ cost) {
    const int row = blockIdx.x;
    const size_t base = (size_t)row * NROW;
    const float fi2 = ft2[row];
    const float x2i = x2[row];
    float acc = 0.f;
    #pragma unroll
    for (int h = 0; h < 16; ++h) {
        int j = threadIdx.x + h * 256;
        float sv = S[base + j];                    // read BEFORE in-place C write
        float p  = exp2f(fmaf(sv, L2E, fi2 + gt2[j]));
        float c  = fmaxf(x2i + y2[j] - sv, 0.f);
        pi[base + j] = p;                          // clobbers Sq region (done with it)
        C[base + j]  = c;
        acc = __fmaf_rn(p, c, acc);
    }
    #pragma unroll
    for (int off = 32; off > 0; off >>= 1) acc += __shfl_down(acc, off);
    __shared__ float sa[4];
    int lane = threadIdx.x & 63, w = threadIdx.x >> 6;
    if (lane == 0) sa[w] = acc;
    __syncthreads();
    if (threadIdx.x == 0)
        atomicAdd(cost, sa[0] + sa[1] + sa[2] + sa[3]);
}

// ---------------------------------------------------------------- launch
extern "C" void kernel_launch(void* const* d_in, const int* in_sizes, int n_in,
                              void* d_out, int out_size, void* d_ws, size_t ws_size,
                              hipStream_t stream) {
    const float* x = (const float*)d_in[0];
    const float* y = (const float*)d_in[1];
    float* out  = (float*)d_out;
    float* cost = out;                 // [1]
    float* pi   = out + 1;             // [NP] floats; holds Sq|SqT (int16) during iters
    float* Cpt  = out + 1 + NP;        // [NP] floats; holds fp32 S during iters
    float* S    = Cpt;
    uint32* Sq  = (uint32*)pi;         // NP/2 uints = 32 MB
    uint32* SqT = Sq + NP/2;           // NP/2 uints = 32 MB (fills pi slot exactly)

    float* ws  = (float*)d_ws;         // small vectors only
    float* x2  = ws;
    float* y2  = ws + NROW;
    float* ft2 = ws + 2 * NROW;        // f~ in base-2 units
    float* gt2 = ws + 3 * NROW;        // g~ in base-2 units

    sqnorm_kernel<<<2048, 256, 0, stream>>>(x, y, x2, y2);
    gemm_kernel<<<dim3(32, 32), 256, 0, stream>>>(x, y, S);
    quantA_kernel<<<2048, 256, 0, stream>>>(S, Sq, cost);
    quantT_kernel<<<dim3(64, 64), 256, 0, stream>>>(S, SqT);
    init_kernel<<<16, 256, 0, stream>>>(y2, gt2);

    void* kargs[] = { (void*)&Sq, (void*)&SqT, (void*)&ft2, (void*)&gt2 };
    hipError_t cerr = hipLaunchCooperativeKernel((void*)sink_iter_kernel,
                                                 dim3(NBLK), dim3(TPB),
                                                 kargs, 0, stream);
    if (cerr != hipSuccess) {
        // fallback: proven 200-dispatch loop
        for (int it = 0; it < 100; ++it) {
            lseq_kernel<<<2048, 256, 0, stream>>>(Sq,  gt2, ft2);
            lseq_kernel<<<2048, 256, 0, stream>>>(SqT, ft2, gt2);
        }
    }

    finalize_kernel<<<NROW, 256, 0, stream>>>(S, ft2, gt2, x2, y2, pi, Cpt, cost);
}

// Round 12
// 3972.034 us; speedup vs baseline: 3.7921x; 1.8372x over previous
//
#include <hip/hip_runtime.h>
#include <cstddef>

#define NROW 4096
#define DIM  512
static const size_t NP = (size_t)NROW * NROW;   // 16777216
#define L2E    1.4426950408889634f
#define ALPHA2 (-12.0f)          // -log2(4096), exact
#define QSCALE 64.0f             // S fp32 -> int16: q = rn(S*64), |S| << 512
#define QD     (1.4426950408889634f / 64.0f)   // dequant * log2e in one fma
#define NBLK   256               // 1 block/CU -- proven cooperative geometry
#define TPB    1024              // 16 waves/block
#define RPB    16                // wave w owns row r0+w
#define UPITCH 1032              // LDS pitch: (q*1032)%32 = q*8 -> 2-way max aliasing

typedef unsigned int uint32;

// ---- agent-scope (L3 coherence point) ops: bypass L1/L2, NO cache maintenance
__device__ __forceinline__ float gloadf(const float* p) {
    return __hip_atomic_load(p, __ATOMIC_RELAXED, __HIP_MEMORY_SCOPE_AGENT);
}
__device__ __forceinline__ void gstoref(float* p, float v) {
    __hip_atomic_store(p, v, __ATOMIC_RELAXED, __HIP_MEMORY_SCOPE_AGENT);
}

// ---------------------------------------------------------------- sq norms
__global__ __launch_bounds__(256) void sqnorm_kernel(const float* __restrict__ x,
                                                     const float* __restrict__ y,
                                                     float* __restrict__ x2,
                                                     float* __restrict__ y2) {
    int gtid = blockIdx.x * 256 + threadIdx.x;
    int wid  = gtid >> 6;
    int lane = gtid & 63;
    const float* src = (wid < NROW) ? x : y;
    float*       dst = (wid < NROW) ? x2 : y2;
    int row = (wid < NROW) ? wid : (wid - NROW);
    const float4* r4 = (const float4*)(src + (size_t)row * DIM);
    float4 a = r4[lane];
    float4 b = r4[lane + 64];
    float s = a.x*a.x + a.y*a.y + a.z*a.z + a.w*a.w
            + b.x*b.x + b.y*b.y + b.z*b.z + b.w*b.w;
    #pragma unroll
    for (int off = 32; off > 0; off >>= 1) s += __shfl_down(s, off);
    if (lane == 0) dst[row] = s;
}

// ---------------------------------------------------------------- S = 2 x y^T  (fp32)
__global__ __launch_bounds__(256) void gemm_kernel(const float* __restrict__ A,
                                                   const float* __restrict__ B,
                                                   float* __restrict__ S) {
    __shared__ float As[16][132];
    __shared__ float Bs[16][132];
    const int bm = blockIdx.y * 128, bn = blockIdx.x * 128;
    const int tid = threadIdx.x;
    const int tx = tid & 15, ty = tid >> 4;
    float acc[8][8];
    #pragma unroll
    for (int i = 0; i < 8; ++i)
        #pragma unroll
        for (int j = 0; j < 8; ++j) acc[i][j] = 0.f;

    for (int kt = 0; kt < DIM; kt += 16) {
        #pragma unroll
        for (int h = 0; h < 2; ++h) {
            int f = tid + h * 256;
            int row = f >> 2, kk = (f & 3) << 2;
            float4 a4 = *(const float4*)(A + (size_t)(bm + row) * DIM + kt + kk);
            As[kk+0][row] = a4.x; As[kk+1][row] = a4.y;
            As[kk+2][row] = a4.z; As[kk+3][row] = a4.w;
            float4 b4 = *(const float4*)(B + (size_t)(bn + row) * DIM + kt + kk);
            Bs[kk+0][row] = b4.x; Bs[kk+1][row] = b4.y;
            Bs[kk+2][row] = b4.z; Bs[kk+3][row] = b4.w;
        }
        __syncthreads();
        #pragma unroll
        for (int k = 0; k < 16; ++k) {
            float ar[8], br[8];
            #pragma unroll
            for (int i = 0; i < 8; ++i) ar[i] = As[k][ty*8 + i];
            #pragma unroll
            for (int j = 0; j < 8; ++j) br[j] = Bs[k][tx*8 + j];
            #pragma unroll
            for (int i = 0; i < 8; ++i)
                #pragma unroll
                for (int j = 0; j < 8; ++j)
                    acc[i][j] = __fmaf_rn(ar[i], br[j], acc[i][j]);
        }
        __syncthreads();
    }
    #pragma unroll
    for (int i = 0; i < 8; ++i) {
        size_t off = (size_t)(bm + ty*8 + i) * NROW + bn + tx*8;
        #pragma unroll
        for (int j = 0; j < 8; ++j) S[off + j] = 2.0f * acc[i][j];
    }
}

// ---------------------------------------------------------------- quantize S -> Sq (+ zero cost)
__global__ __launch_bounds__(256) void quantA_kernel(const float* __restrict__ S,
                                                     uint32* __restrict__ Sq,
                                                     float* __restrict__ cost) {
    if (blockIdx.x == 0 && threadIdx.x == 0) cost[0] = 0.f;
    size_t i = (size_t)blockIdx.x * 256 + threadIdx.x;
    const size_t nu = NP / 2, stride = (size_t)2048 * 256;
    for (; i < nu; i += stride) {
        float a = S[2*i], b = S[2*i + 1];
        float qa = fmaxf(fminf(a * QSCALE,  32767.f), -32767.f);
        float qb = fmaxf(fminf(b * QSCALE,  32767.f), -32767.f);
        int ia = __float2int_rn(qa), ib = __float2int_rn(qb);
        Sq[i] = (uint32)(ia & 0xffff) | ((uint32)ib << 16);
    }
}

// ---------------------------------------------------------------- quantize+transpose S -> SqT
__global__ __launch_bounds__(256) void quantT_kernel(const float* __restrict__ S,
                                                     uint32* __restrict__ SqT) {
    __shared__ short tile[64][66];
    const int bx = blockIdx.x * 64, by = blockIdx.y * 64;
    const int t = threadIdx.x;
    const int c = t & 63, r0 = t >> 6;
    #pragma unroll
    for (int rr = 0; rr < 16; ++rr) {
        int r = r0 + rr * 4;
        float v = S[(size_t)(by + r) * NROW + bx + c];
        float q = fmaxf(fminf(v * QSCALE, 32767.f), -32767.f);
        tile[r][c] = (short)__float2int_rn(q);
    }
    __syncthreads();
    const int p = t & 31, jl = t >> 5;
    #pragma unroll
    for (int jj = 0; jj < 8; ++jj) {
        int j = jj * 8 + jl;
        uint32 lo = (unsigned short)tile[2*p    ][j];
        uint32 hi = (unsigned short)tile[2*p + 1][j];
        SqT[(size_t)(bx + j) * (NROW/2) + (by >> 1) + p] = lo | (hi << 16);
    }
}

// ---------------------------------------------------------------- init (gt2 + barrier counter)
__global__ void init_kernel(const float* __restrict__ y2,
                            float* __restrict__ gt2,
                            uint32* __restrict__ bar) {
    int i = blockIdx.x * 256 + threadIdx.x;
    if (i < NROW) gt2[i] = -y2[i] * L2E;       // g~0 = -y2, base-2 units
    if (i == 0) *bar = 0u;                     // d_ws is poisoned each launch
}

// ---------------------------------------------------------------- no-L2-invalidate grid barrier
// Protocol: every wave has already done s_waitcnt vmcnt(0) after its agent-scope
// o2 store (store reached L3). Then block-sync, thread 0 arrives with a RELAXED
// agent-scope add and spins on a RELAXED agent-scope load. No fences -> no
// buffer_wbl2 / buffer_inv -> Sq stays L2-resident across all 200 phases.
__device__ __forceinline__ void gbar(uint32* bar, uint32 target, int t) {
    __syncthreads();
    if (t == 0) {
        asm volatile("s_waitcnt vmcnt(0)" ::: "memory");
        __hip_atomic_fetch_add(bar, 1u, __ATOMIC_RELAXED, __HIP_MEMORY_SCOPE_AGENT);
        int spins = 0;
        while (__hip_atomic_load(bar, __ATOMIC_RELAXED, __HIP_MEMORY_SCOPE_AGENT) < target) {
            __builtin_amdgcn_s_sleep(2);
            if (++spins > 16384) break;        // fail visibly, never hang
        }
    }
    __syncthreads();
}

// ---------------------------------------------------------------- fused-iteration lse phase
// Wave w reduces row r0+w fully in-wave. u staged in LDS deinterleaved by (j&3),
// pitch 1032 (2-way max bank aliasing). NT: non-temporal matrix loads (SqT path)
// so the g-phase stream does not evict the L2-resident Sq slices.
template<bool NT>
__device__ __forceinline__ void lse_phase(const uint32* __restrict__ Q,
                                          const float* __restrict__ u2,
                                          float* __restrict__ o2,
                                          float* __restrict__ ulds,
                                          int r0, int t, int w, int lane) {
    // stage u (16 KB) via coalesced agent-scope loads (u lives at L3)
    float e0 = gloadf(u2 + t);
    float e1 = gloadf(u2 + t + 1024);
    float e2 = gloadf(u2 + t + 2048);
    float e3 = gloadf(u2 + t + 3072);
    int sb = (t & 3) * UPITCH + (t >> 2);      // element t+1024q -> slot (t&3), k=(t>>2)+256q
    ulds[sb      ] = e0;
    ulds[sb + 256] = e1;
    ulds[sb + 512] = e2;
    ulds[sb + 768] = e3;
    __syncthreads();

    const uint2* q2 = (const uint2*)(Q + (size_t)(r0 + w) * (NROW/2));
    uint2 wv[16];
    #pragma unroll
    for (int h = 0; h < 16; ++h) {             // all 16 loads in flight (MLP)
        if (NT) {
            unsigned long long v = __builtin_nontemporal_load(
                (const unsigned long long*)(q2 + lane + h * 64));
            wv[h].x = (uint32)v; wv[h].y = (uint32)(v >> 32);
        } else {
            wv[h] = q2[lane + h * 64];
        }
    }
    float m = -1e30f, s = 0.f;
    #pragma unroll
    for (int h = 0; h < 16; ++h) {
        int k2 = lane + h * 64;                // uint2 index: elements 4k2..4k2+3
        float a0 = (float)(int)(short)(wv[h].x & 0xffffu);
        float b0 = (float)((int)wv[h].x >> 16);
        float a1 = (float)(int)(short)(wv[h].y & 0xffffu);
        float b1 = (float)((int)wv[h].y >> 16);
        float v0 = fmaf(a0, QD, ulds[k2]);
        float v1 = fmaf(b0, QD, ulds[UPITCH + k2]);
        float v2 = fmaf(a1, QD, ulds[2 * UPITCH + k2]);
        float v3 = fmaf(b1, QD, ulds[3 * UPITCH + k2]);
        float vm = fmaxf(fmaxf(v0, v1), fmaxf(v2, v3));
        if (__any(vm > m + 60.f)) {            // rare wave-uniform rescale
            float mn = fmaxf(m, vm);
            s *= exp2f(m - mn); m = mn;
        }
        s += (exp2f(v0 - m) + exp2f(v1 - m)) + (exp2f(v2 - m) + exp2f(v3 - m));
    }
    // 64-lane butterfly merge
    #pragma unroll
    for (int off = 1; off < 64; off <<= 1) {
        float mo = __shfl_xor(m, off), so = __shfl_xor(s, off);
        float d = m - mo;
        float e = exp2f(-fabsf(d));
        s = (d > 0.f) ? fmaf(so, e, s) : fmaf(s, e, so);
        m = fmaxf(m, mo);
    }
    if (lane == 0) gstoref(&o2[r0 + w], ALPHA2 - (m + __log2f(s)));
    asm volatile("s_waitcnt vmcnt(0)" ::: "memory");  // o2 store has reached L3
}

__global__ __launch_bounds__(TPB) void sink_iter_kernel(
        const uint32* __restrict__ Sq, const uint32* __restrict__ SqT,
        float* __restrict__ ft2, float* __restrict__ gt2,
        uint32* __restrict__ bar) {
    __shared__ float ulds[4 * UPITCH];
    const int t = threadIdx.x;
    const int w = t >> 6, lane = t & 63;
    const int r0 = blockIdx.x * RPB;
    uint32 tgt = 0;
    for (int it = 0; it < 100; ++it) {
        lse_phase<false>(Sq,  gt2, ft2, ulds, r0, t, w, lane);   // f update (L2-hot)
        tgt += NBLK; gbar(bar, tgt, t);
        lse_phase<true >(SqT, ft2, gt2, ulds, r0, t, w, lane);   // g update (NT stream)
        tgt += NBLK; gbar(bar, tgt, t);
    }
}

// ---------------------------------------------------------------- fallback lse pass (proven)
__global__ __launch_bounds__(256) void lseq_kernel(const uint32* __restrict__ Q,
                                                   const float* __restrict__ u2,
                                                   float* __restrict__ o2) {
    const int r0 = blockIdx.x * 2;
    const uint32* q0 = Q + (size_t)r0 * (NROW/2);
    const uint32* q1 = q0 + (NROW/2);
    const int t = threadIdx.x;
    float m0 = -1e30f, s0 = 0.f, m1 = -1e30f, s1 = 0.f;
    #pragma unroll 2
    for (int h = 0; h < 8; ++h) {
        int k = t + h * 256;
        float2 uu = *(const float2*)(u2 + 2*k);
        uint32 w0 = q0[k], w1 = q1[k];
        float a0 = (float)(int)(short)(w0 & 0xffffu);
        float b0 = (float)((int)w0 >> 16);
        float a1 = (float)(int)(short)(w1 & 0xffffu);
        float b1 = (float)((int)w1 >> 16);
        float v00 = fmaf(a0, QD, uu.x), v01 = fmaf(b0, QD, uu.y);
        float v10 = fmaf(a1, QD, uu.x), v11 = fmaf(b1, QD, uu.y);
        float vm0 = fmaxf(v00, v01), vm1 = fmaxf(v10, v11);
        if (__any(vm0 > m0 + 60.f)) {
            float mn = fmaxf(m0, vm0);
            s0 *= exp2f(m0 - mn); m0 = mn;
        }
        if (__any(vm1 > m1 + 60.f)) {
            float mn = fmaxf(m1, vm1);
            s1 *= exp2f(m1 - mn); m1 = mn;
        }
        s0 += exp2f(v00 - m0) + exp2f(v01 - m0);
        s1 += exp2f(v10 - m1) + exp2f(v11 - m1);
    }
    #pragma unroll
    for (int off = 1; off < 64; off <<= 1) {
        float mo = __shfl_xor(m0, off), so = __shfl_xor(s0, off);
        float d = m0 - mo;
        float e = exp2f(-fabsf(d));
        s0 = (d > 0.f) ? fmaf(so, e, s0) : fmaf(s0, e, so);
        m0 = fmaxf(m0, mo);
        float mo1 = __shfl_xor(m1, off), so1 = __shfl_xor(s1, off);
        float d1 = m1 - mo1;
        float e1 = exp2f(-fabsf(d1));
        s1 = (d1 > 0.f) ? fmaf(so1, e1, s1) : fmaf(s1, e1, so1);
        m1 = fmaxf(m1, mo1);
    }
    __shared__ float sm0[4], ss0[4], sm1[4], ss1[4];
    int lane = t & 63, w = t >> 6;
    if (lane == 0) { sm0[w] = m0; ss0[w] = s0; sm1[w] = m1; ss1[w] = s1; }
    __syncthreads();
    if (t == 0) {
        float M0 = sm0[0], S0 = ss0[0], M1 = sm1[0], S1 = ss1[0];
        #pragma unroll
        for (int ww = 1; ww < 4; ++ww) {
            float d = M0 - sm0[ww];
            float e = exp2f(-fabsf(d));
            S0 = (d > 0.f) ? fmaf(ss0[ww], e, S0) : fmaf(S0, e, ss0[ww]);
            M0 = fmaxf(M0, sm0[ww]);
            float d1 = M1 - sm1[ww];
            float e1 = exp2f(-fabsf(d1));
            S1 = (d1 > 0.f) ? fmaf(ss1[ww], e1, S1) : fmaf(S1, e1, ss1[ww]);
            M1 = fmaxf(M1, sm1[ww]);
        }
        o2[r0]     = ALPHA2 - (M0 + __log2f(S0));
        o2[r0 + 1] = ALPHA2 - (M1 + __log2f(S1));
    }
}

// ---------------------------------------------------------------- finalize
__global__ __launch_bounds__(256) void finalize_kernel(const float* __restrict__ S,
                                                       const float* __restrict__ ft2,
                                                       const float* __restrict__ gt2,
                                                       const float* __restrict__ x2,
                                                       const float* __restrict__ y2,
                                                       float* __restrict__ pi,
                                                       float* __restrict__ C,
                                                       float* __restrict__ cost) {
    const int row = blockIdx.x;
    const size_t base = (size_t)row * NROW;
    const float fi2 = ft2[row];
    const float x2i = x2[row];
    float acc = 0.f;
    #pragma unroll
    for (int h = 0; h < 16; ++h) {
        int j = threadIdx.x + h * 256;
        float sv = S[base + j];                    // read BEFORE in-place C write
        float p  = exp2f(fmaf(sv, L2E, fi2 + gt2[j]));
        float c  = fmaxf(x2i + y2[j] - sv, 0.f);
        pi[base + j] = p;
        C[base + j]  = c;
        acc = __fmaf_rn(p, c, acc);
    }
    #pragma unroll
    for (int off = 32; off > 0; off >>= 1) acc += __shfl_down(acc, off);
    __shared__ float sa[4];
    int lane = threadIdx.x & 63, w = threadIdx.x >> 6;
    if (lane == 0) sa[w] = acc;
    __syncthreads();
    if (threadIdx.x == 0)
        atomicAdd(cost, sa[0] + sa[1] + sa[2] + sa[3]);
}

// ---------------------------------------------------------------- launch
extern "C" void kernel_launch(void* const* d_in, const int* in_sizes, int n_in,
                              void* d_out, int out_size, void* d_ws, size_t ws_size,
                              hipStream_t stream) {
    const float* x = (const float*)d_in[0];
    const float* y = (const float*)d_in[1];
    float* out  = (float*)d_out;
    float* cost = out;                 // [1]
    float* pi   = out + 1;             // [NP] floats; holds Sq|SqT (int16) during iters
    float* Cpt  = out + 1 + NP;        // [NP] floats; holds fp32 S during iters
    float* S    = Cpt;
    uint32* Sq  = (uint32*)pi;         // NP/2 uints = 32 MB
    uint32* SqT = Sq + NP/2;           // NP/2 uints = 32 MB

    float* ws  = (float*)d_ws;
    float* x2  = ws;
    float* y2  = ws + NROW;
    float* ft2 = ws + 2 * NROW;        // f~ in base-2 units
    float* gt2 = ws + 3 * NROW;        // g~ in base-2 units
    uint32* bar = (uint32*)(ws + 4 * NROW);   // barrier counter (init zeroes it)

    sqnorm_kernel<<<2048, 256, 0, stream>>>(x, y, x2, y2);
    gemm_kernel<<<dim3(32, 32), 256, 0, stream>>>(x, y, S);
    quantA_kernel<<<2048, 256, 0, stream>>>(S, Sq, cost);
    quantT_kernel<<<dim3(64, 64), 256, 0, stream>>>(S, SqT);
    init_kernel<<<16, 256, 0, stream>>>(y2, gt2, bar);

    void* kargs[] = { (void*)&Sq, (void*)&SqT, (void*)&ft2, (void*)&gt2, (void*)&bar };
    hipError_t cerr = hipLaunchCooperativeKernel((void*)sink_iter_kernel,
                                                 dim3(NBLK), dim3(TPB),
                                                 kargs, 0, stream);
    if (cerr != hipSuccess) {
        // fallback: proven 200-dispatch loop
        for (int it = 0; it < 100; ++it) {
            lseq_kernel<<<2048, 256, 0, stream>>>(Sq,  gt2, ft2);
            lseq_kernel<<<2048, 256, 0, stream>>>(SqT, ft2, gt2);
        }
    }

    finalize_kernel<<<NROW, 256, 0, stream>>>(S, ft2, gt2, x2, y2, pi, Cpt, cost);
}